// Round 8
// baseline (13283.539 us; speedup 1.0000x reference)
//
#include <hip/hip_runtime.h>

#define HSTEPS 8640
#define HID 128
#define BATCH 16
#define NTHR 256
#define YRING 192

typedef _Float16 h16;
typedef __attribute__((ext_vector_type(8))) _Float16 h16x8;
typedef __attribute__((ext_vector_type(4))) float f32x4;

static __device__ __forceinline__ float sigm(float x) {
    return __builtin_amdgcn_rcpf(1.0f + __expf(-x));
}
static __device__ __forceinline__ float tanh_f(float x) {
    float ax = __builtin_fabsf(x);
    float ee = __expf(2.0f * ax);
    float r = 1.0f - 2.0f * __builtin_amdgcn_rcpf(ee + 1.0f);
    return __builtin_copysignf(r, x);
}
template <int CTRL>
static __device__ __forceinline__ float dppmov(float x) {
    return __int_as_float(
        __builtin_amdgcn_mov_dpp(__float_as_int(x), CTRL, 0xF, 0xF, false));
}
// sum of 4-periodic values -> every lane holds its 4-group total
static __device__ __forceinline__ float sum4(float x) {
    x += dppmov<0x121>(x);
    x += dppmov<0x122>(x);
    return x;
}
// full wave64 sum -> total lands in lane 63
static __device__ __forceinline__ float red_wave(float x) {
    x += dppmov<0x121>(x);
    x += dppmov<0x122>(x);
    x += dppmov<0x124>(x);
    x += dppmov<0x128>(x);
    float t1 = __int_as_float(__builtin_amdgcn_update_dpp(
        0, __float_as_int(x), 0x142 /*row_bcast15*/, 0xA, 0xF, false));
    x += t1;
    float t2 = __int_as_float(__builtin_amdgcn_update_dpp(
        0, __float_as_int(x), 0x143 /*row_bcast31*/, 0xC, 0xF, false));
    x += t2;
    return x;
}

// ---- weight fragments: 96 named h16x8 = 384 regs/lane (MFMA-B only) ----
#define FRAG_C(F, m, g, mb) F(m, g, mb, 0) F(m, g, mb, 1) F(m, g, mb, 2) F(m, g, mb, 3)
#define FRAG_MB(F, m, g) FRAG_C(F, m, g, 0) FRAG_C(F, m, g, 1)
#define FRAG_G(F, m) FRAG_MB(F, m, 0) FRAG_MB(F, m, 1) FRAG_MB(F, m, 2) FRAG_MB(F, m, 3)
#define FRAG_ALL(F) FRAG_G(F, 0) FRAG_G(F, 1) FRAG_G(F, 2)

#define DECLF(m, g, mb, c) h16x8 wf##m##_##g##_##mb##_##c;

#define WPTR0 Whh0
#define WPTR1 Wih1
#define WPTR2 Whh1
// B[k][n]: lane l holds W[128g + 16(2wv+mb) + (l&15)][32c + 8*(l>>4) + j]
#define LOADF(m, g, mb, c)                                                     \
    {                                                                          \
        const float* p_ = WPTR##m +                                            \
            (size_t)((128 * g + 16 * (2 * wv + mb) + ln15) * HID + 32 * c +    \
                     8 * grp);                                                 \
        float4 u_ = *(const float4*)p_;                                        \
        float4 v_ = *(const float4*)(p_ + 4);                                  \
        wf##m##_##g##_##mb##_##c =                                             \
            h16x8{(h16)u_.x, (h16)u_.y, (h16)u_.z, (h16)u_.w,                  \
                  (h16)v_.x, (h16)v_.y, (h16)v_.z, (h16)v_.w};                 \
    }

#define MF1(Q, av, m, g, mb, c)                                                \
    Q = __builtin_amdgcn_mfma_f32_16x16x32_f16((av), wf##m##_##g##_##mb##_##c, \
                                               (Q), 0, 0, 0);
// one h-chunk feeds all 8 chains (4 gates x 2 element-blocks)
#define MF_CHUNK(av, m, c, P)                                                  \
    MF1(P##0_0, av, m, 0, 0, c) MF1(P##1_0, av, m, 1, 0, c)                    \
    MF1(P##2_0, av, m, 2, 0, c) MF1(P##3_0, av, m, 3, 0, c)                    \
    MF1(P##0_1, av, m, 0, 1, c) MF1(P##1_1, av, m, 1, 1, c)                    \
    MF1(P##2_1, av, m, 2, 1, c) MF1(P##3_1, av, m, 3, 1, c)

// One block per batch; 256 threads = 4 waves = 1 wave/SIMD (512-reg budget).
// Wave wv owns elements [32wv, 32wv+32): fragments for 2 element-blocks x
// 4 gates x 4 K-chunks x 3 matrices = 384 regs -> AGPR side, spill-free.
// Lane l: element e = 32wv + 16*(l>>5) + (l&15); lanes with l&16 duplicate.
__global__ __launch_bounds__(NTHR, 1) void lstm2_kernel(
    const float* __restrict__ y0, const float* __restrict__ h0in,
    const float* __restrict__ c0in, const float* __restrict__ Wih0,
    const float* __restrict__ Whh0, const float* __restrict__ bih0,
    const float* __restrict__ bhh0, const float* __restrict__ Wih1,
    const float* __restrict__ Whh1, const float* __restrict__ bih1,
    const float* __restrict__ bhh1, const float* __restrict__ fcw,
    const float* __restrict__ fcb, float* __restrict__ out) {
    const int b = blockIdx.x;
    const int t = threadIdx.x;
    const int wv = t >> 6;          // wave 0..3
    const int ln = t & 63;          // lane
    const int grp = ln >> 4;        // k-slot 0..3
    const int ln15 = ln & 15;       // column within tile
    const int e = 32 * wv + ((ln & 32) >> 1) + ln15;  // owned element
    const bool dup = (ln & 16) != 0;                  // duplicate lane

    // hsm: [0..127]=h0 buf0, [128..255]=h0 buf1, [256..383]=h1 buf0, [384..511]=h1 buf1
    __shared__ __align__(16) h16 hsm[512];
    __shared__ float ypartbuf[4];
    __shared__ float ybuf[YRING];

    FRAG_ALL(DECLF)
    FRAG_ALL(LOADF)

    const float bias0_0 = bih0[e] + bhh0[e];
    const float bias0_1 = bih0[128 + e] + bhh0[128 + e];
    const float bias0_2 = bih0[256 + e] + bhh0[256 + e];
    const float bias0_3 = bih0[384 + e] + bhh0[384 + e];
    const float bias1_0 = bih1[e] + bhh1[e];
    const float bias1_1 = bih1[128 + e] + bhh1[128 + e];
    const float bias1_2 = bih1[256 + e] + bhh1[256 + e];
    const float bias1_3 = bih1[384 + e] + bhh1[384 + e];
    const float wih0_0 = Wih0[e];
    const float wih0_1 = Wih0[128 + e];
    const float wih0_2 = Wih0[256 + e];
    const float wih0_3 = Wih0[384 + e];
    const float fcb_ = fcb[0];
    const float fcw_e = fcw[e];

    float c0v = c0in[b * HID + e];            // replicated on dup lanes
    float c1v = c0in[(BATCH + b) * HID + e];  // replicated on dup lanes

    if (t < HID) {
        hsm[t] = (h16)h0in[b * HID + t];
        hsm[256 + t] = (h16)h0in[(BATCH + b) * HID + t];
    }
    if (t < 4) ypartbuf[t] = (t == 0) ? (y0[b] - fcb_) : 0.0f;
    __syncthreads();

    const f32x4 zq = {0.f, 0.f, 0.f, 0.f};
    float* outb = out + (size_t)b * HSTEPS;
    int p = 0;
    int ys = 0;
    int flush_at = YRING;

#pragma unroll 1
    for (int s = 0; s < HSTEPS; ++s) {
        const int hp0 = 8 * grp + 128 * p;  // h0 buf p, this lane's k-slice

        // ---- issue phase-A operand loads first (latency hides under y) ----
        h16x8 a0 = *(const h16x8*)&hsm[hp0 + 0];
        h16x8 a1 = *(const h16x8*)&hsm[hp0 + 32];
        h16x8 a2 = *(const h16x8*)&hsm[hp0 + 64];
        h16x8 a3 = *(const h16x8*)&hsm[hp0 + 96];

        // ---- y = fc output of previous step ----
        float yv = sum4(ypartbuf[ln & 3]) + fcb_;
        if (s > 0) {
            if (t == 0) ybuf[ys] = yv;
            ys = (ys == YRING - 1) ? 0 : ys + 1;
        }

        // ---- phase A: gates0 = Whh0 @ h0_prev (+ Wih0*y + bias0) ----
        f32x4 pA0_0 = zq, pA1_0 = zq, pA2_0 = zq, pA3_0 = zq;
        f32x4 pA0_1 = zq, pA1_1 = zq, pA2_1 = zq, pA3_1 = zq;
        MF_CHUNK(a0, 0, 0, pA)
        MF_CHUNK(a1, 0, 1, pA)
        MF_CHUNK(a2, 0, 2, pA)
        MF_CHUNK(a3, 0, 3, pA)

        const bool mb1 = (ln & 32) != 0;
        float G0 = (mb1 ? pA0_1[0] : pA0_0[0]) + __builtin_fmaf(wih0_0, yv, bias0_0);
        float G1 = (mb1 ? pA1_1[0] : pA1_0[0]) + __builtin_fmaf(wih0_1, yv, bias0_1);
        float G2 = (mb1 ? pA2_1[0] : pA2_0[0]) + __builtin_fmaf(wih0_2, yv, bias0_2);
        float G3 = (mb1 ? pA3_1[0] : pA3_0[0]) + __builtin_fmaf(wih0_3, yv, bias0_3);
        float si = sigm(G0), sf = sigm(G1), so = sigm(G3);
        float tg = tanh_f(G2);
        c0v = __builtin_fmaf(sf, c0v, si * tg);
        float h0nv = so * tanh_f(c0v);
        if (!dup) hsm[(p ^ 1) * 128 + e] = (h16)h0nv;
        __syncthreads();  // B1: h0 new ready

        // ---- periodic output flush (uniform, 1/192 steps) ----
        if (s == flush_at) {
            if (t < YRING) outb[flush_at - YRING + t] = ybuf[t];
            flush_at += YRING;
        }

        // ---- phase B: gates1 = Whh1 @ h1_prev + Wih1 @ h0n + bias1 ----
        const int hb = hp0 ^ 128;  // h0 buf p^1
        h16x8 b0 = *(const h16x8*)&hsm[hp0 + 256];
        h16x8 b1 = *(const h16x8*)&hsm[hp0 + 288];
        h16x8 b2 = *(const h16x8*)&hsm[hp0 + 320];
        h16x8 b3 = *(const h16x8*)&hsm[hp0 + 352];
        h16x8 d0 = *(const h16x8*)&hsm[hb + 0];
        h16x8 d1 = *(const h16x8*)&hsm[hb + 32];
        h16x8 d2 = *(const h16x8*)&hsm[hb + 64];
        h16x8 d3 = *(const h16x8*)&hsm[hb + 96];
        f32x4 pB0_0 = zq, pB1_0 = zq, pB2_0 = zq, pB3_0 = zq;
        f32x4 pB0_1 = zq, pB1_1 = zq, pB2_1 = zq, pB3_1 = zq;
        MF_CHUNK(b0, 2, 0, pB)
        MF_CHUNK(b1, 2, 1, pB)
        MF_CHUNK(b2, 2, 2, pB)
        MF_CHUNK(b3, 2, 3, pB)
        MF_CHUNK(d0, 1, 0, pB)
        MF_CHUNK(d1, 1, 1, pB)
        MF_CHUNK(d2, 1, 2, pB)
        MF_CHUNK(d3, 1, 3, pB)

        float H0 = (mb1 ? pB0_1[0] : pB0_0[0]) + bias1_0;
        float H1 = (mb1 ? pB1_1[0] : pB1_0[0]) + bias1_1;
        float H2 = (mb1 ? pB2_1[0] : pB2_0[0]) + bias1_2;
        float H3 = (mb1 ? pB3_1[0] : pB3_0[0]) + bias1_3;
        float ti = sigm(H0), tf = sigm(H1), to = sigm(H3);
        float tgg = tanh_f(H2);
        c1v = __builtin_fmaf(tf, c1v, ti * tgg);
        float h1nv = to * tanh_f(c1v);
        if (!dup) hsm[256 + (p ^ 1) * 128 + e] = (h16)h1nv;

        // ---- fused fc: one contribution per element, wave-reduce ----
        float part = red_wave(dup ? 0.0f : fcw_e * h1nv);
        if (ln == 63) ypartbuf[wv] = part;

        p ^= 1;
        __syncthreads();  // B2: h1/ypart ready
    }

    // ---- tail: y(8639) + final flush ----
    float yv = sum4(ypartbuf[ln & 3]) + fcb_;
    if (t == 0) ybuf[YRING - 1] = yv;
    __syncthreads();
    if (t < YRING) outb[HSTEPS - YRING + t] = ybuf[t];
}

extern "C" void kernel_launch(void* const* d_in, const int* in_sizes, int n_in,
                              void* d_out, int out_size, void* d_ws,
                              size_t ws_size, hipStream_t stream) {
    const float* y0 = (const float*)d_in[0];
    const float* h0 = (const float*)d_in[1];
    const float* c0 = (const float*)d_in[2];
    const float* Wih0 = (const float*)d_in[3];
    const float* Whh0 = (const float*)d_in[4];
    const float* bih0 = (const float*)d_in[5];
    const float* bhh0 = (const float*)d_in[6];
    const float* Wih1 = (const float*)d_in[7];
    const float* Whh1 = (const float*)d_in[8];
    const float* bih1 = (const float*)d_in[9];
    const float* bhh1 = (const float*)d_in[10];
    const float* fcw = (const float*)d_in[11];
    const float* fcb = (const float*)d_in[12];
    float* out = (float*)d_out;

    lstm2_kernel<<<dim3(BATCH), dim3(NTHR), 0, stream>>>(
        y0, h0, c0, Wih0, Whh0, bih0, bhh0, Wih1, Whh1, bih1, bhh1, fcw, fcb,
        out);
}

// Round 9
// 10689.467 us; speedup vs baseline: 1.2427x; 1.2427x over previous
//
#include <hip/hip_runtime.h>

#define HSTEPS 8640
#define HID 128
#define BATCH 16
#define NTHR 512
#define YRING 192

typedef _Float16 h16;
typedef __attribute__((ext_vector_type(8))) _Float16 h16x8;
typedef __attribute__((ext_vector_type(4))) float f32x4;

static __device__ __forceinline__ float sigm(float x) {
    return __builtin_amdgcn_rcpf(1.0f + __expf(-x));
}
static __device__ __forceinline__ float tanh_f(float x) {
    float ax = __builtin_fabsf(x);
    float ee = __expf(2.0f * ax);
    float r = 1.0f - 2.0f * __builtin_amdgcn_rcpf(ee + 1.0f);
    return __builtin_copysignf(r, x);
}
template <int CTRL>
static __device__ __forceinline__ float dppmov(float x) {
    return __int_as_float(
        __builtin_amdgcn_mov_dpp(__float_as_int(x), CTRL, 0xF, 0xF, false));
}
// sum of 8-periodic values -> every lane holds the 8-group total
static __device__ __forceinline__ float sum8(float x) {
    x += dppmov<0x121>(x);
    x += dppmov<0x122>(x);
    x += dppmov<0x124>(x);
    return x;
}
// sum across each 16-lane row -> every lane holds its row's sum
static __device__ __forceinline__ float sum16(float x) {
    x += dppmov<0x121>(x);
    x += dppmov<0x122>(x);
    x += dppmov<0x124>(x);
    x += dppmov<0x128>(x);
    return x;
}

// ---- weight fragments: 48 named h16x8 (MFMA-B only -> AGPR-eligible) ----
#define FRAG_GC(F, m, g) F(m, g, 0) F(m, g, 1) F(m, g, 2) F(m, g, 3)
#define FRAG_M(F, m) FRAG_GC(F, m, 0) FRAG_GC(F, m, 1) FRAG_GC(F, m, 2) FRAG_GC(F, m, 3)
#define FRAG_ALL(F) FRAG_M(F, 0) FRAG_M(F, 1) FRAG_M(F, 2)

#define DECLF(m, g, c) h16x8 wf##m##_##g##_##c;

#define WPTR0 Whh0
#define WPTR1 Wih1
#define WPTR2 Whh1
// B[k][n]: lane l holds W[16*(wv+8g) + (l&15)][32c + 8*(l>>4) + j], j=0..7
#define LOADF(m, g, c)                                                         \
    {                                                                          \
        const float* p_ = WPTR##m +                                            \
            (size_t)((16 * (wv + 8 * g) + ln15) * HID + 32 * c + 8 * grp);     \
        float4 u_ = *(const float4*)p_;                                        \
        float4 v_ = *(const float4*)(p_ + 4);                                  \
        wf##m##_##g##_##c = h16x8{(h16)u_.x, (h16)u_.y, (h16)u_.z, (h16)u_.w,  \
                                  (h16)v_.x, (h16)v_.y, (h16)v_.z, (h16)v_.w}; \
    }

#define MFMA(q, a, b) \
    q = __builtin_amdgcn_mfma_f32_16x16x32_f16((a), (b), (q), 0, 0, 0)

#define CHAIN(qv, m, g, r0, r1, r2, r3) \
    qv = zq;                            \
    MFMA(qv, r0, wf##m##_##g##_0);      \
    MFMA(qv, r1, wf##m##_##g##_1);      \
    MFMA(qv, r2, wf##m##_##g##_2);      \
    MFMA(qv, r3, wf##m##_##g##_3);
#define CHAIN_CONT(qv, m, g, r0, r1, r2, r3) \
    MFMA(qv, r0, wf##m##_##g##_0);           \
    MFMA(qv, r1, wf##m##_##g##_1);           \
    MFMA(qv, r2, wf##m##_##g##_2);           \
    MFMA(qv, r3, wf##m##_##g##_3);

// One block per batch; 512 threads = 8 waves, 2/SIMD. Round-6 layout (proven)
// + software-pipelined loop: Whh0 for step s+1 issues in phase B of step s
// (same A-operands as Wih1), so act0/act1/fc VALU hide under MFMA issue and
// act0 never waits on a just-issued chain.
__global__ __launch_bounds__(NTHR, 2) void lstm2_kernel(
    const float* __restrict__ y0, const float* __restrict__ h0in,
    const float* __restrict__ c0in, const float* __restrict__ Wih0,
    const float* __restrict__ Whh0, const float* __restrict__ bih0,
    const float* __restrict__ bhh0, const float* __restrict__ Wih1,
    const float* __restrict__ Whh1, const float* __restrict__ bih1,
    const float* __restrict__ bhh1, const float* __restrict__ fcw,
    const float* __restrict__ fcb, float* __restrict__ out) {
    const int b = blockIdx.x;
    const int t = threadIdx.x;
    const int wv = t >> 6;     // wave 0..7
    const int ln = t & 63;     // lane
    const int grp = ln >> 4;   // k-group 0..3
    const int ln15 = ln & 15;  // element-within-wave / B col
    const int ev = 16 * wv + ln15;  // this lane's element 0..127

    // hsm: [0..127]=h0 buf0, [128..255]=h0 buf1, [256..383]=h1 buf0, [384..511]=h1 buf1
    __shared__ __align__(16) h16 hsm[512];
    __shared__ float ypartbuf[8];
    __shared__ float ybuf[YRING];

    FRAG_ALL(DECLF)
    FRAG_ALL(LOADF)

    const float bias0_0 = bih0[ev] + bhh0[ev];
    const float bias0_1 = bih0[128 + ev] + bhh0[128 + ev];
    const float bias0_2 = bih0[256 + ev] + bhh0[256 + ev];
    const float bias0_3 = bih0[384 + ev] + bhh0[384 + ev];
    const float bias1_0 = bih1[ev] + bhh1[ev];
    const float bias1_1 = bih1[128 + ev] + bhh1[128 + ev];
    const float bias1_2 = bih1[256 + ev] + bhh1[256 + ev];
    const float bias1_3 = bih1[384 + ev] + bhh1[384 + ev];
    const float wih0_0 = Wih0[ev];
    const float wih0_1 = Wih0[128 + ev];
    const float wih0_2 = Wih0[256 + ev];
    const float wih0_3 = Wih0[384 + ev];
    const float fcb_ = fcb[0];
    const float fcw_e = fcw[ev];

    float c0v = c0in[b * HID + ev];            // replicated across k-groups
    float c1v = c0in[(BATCH + b) * HID + ev];  // replicated across k-groups

    if (ln < 16) {
        hsm[ev] = (h16)h0in[b * HID + ev];
        hsm[256 + ev] = (h16)h0in[(BATCH + b) * HID + ev];
    }
    __syncthreads();

    const f32x4 zq = {0.f, 0.f, 0.f, 0.f};
    float* outb = out + (size_t)b * HSTEPS;

    // ---- prologue: q0 = Whh0 @ h0_in(0); y_in(0) = y0 ----
    float yv = y0[b];
    f32x4 q0_0, q0_1, q0_2, q0_3;
    {
        const int hp = 8 * grp;  // h0 buf 0
        h16x8 a0 = *(const h16x8*)&hsm[hp + 0];
        h16x8 a1 = *(const h16x8*)&hsm[hp + 32];
        h16x8 a2 = *(const h16x8*)&hsm[hp + 64];
        h16x8 a3 = *(const h16x8*)&hsm[hp + 96];
        CHAIN(q0_0, 0, 0, a0, a1, a2, a3)
        CHAIN(q0_1, 0, 1, a0, a1, a2, a3)
        CHAIN(q0_2, 0, 2, a0, a1, a2, a3)
        CHAIN(q0_3, 0, 3, a0, a1, a2, a3)
    }

    int p = 0;
    int ys = 0;
    int flush_at = YRING;

#pragma unroll 1
    for (int s = 0; s < HSTEPS; ++s) {
        const int hp0 = 8 * grp + 128 * p;

        // ---- issue Whh1 @ h1_in(s) (independent of act0) ----
        h16x8 b0 = *(const h16x8*)&hsm[hp0 + 256];
        h16x8 b1 = *(const h16x8*)&hsm[hp0 + 288];
        h16x8 b2 = *(const h16x8*)&hsm[hp0 + 320];
        h16x8 b3 = *(const h16x8*)&hsm[hp0 + 352];
        f32x4 q1_0, q1_1, q1_2, q1_3;
        CHAIN(q1_0, 2, 0, b0, b1, b2, b3)
        CHAIN(q1_1, 2, 1, b0, b1, b2, b3)
        CHAIN(q1_2, 2, 2, b0, b1, b2, b3)
        CHAIN(q1_3, 2, 3, b0, b1, b2, b3)

        // ---- act0: q0 is from last iteration (chain long drained) ----
        float G0 = q0_0[0] + __builtin_fmaf(wih0_0, yv, bias0_0);
        float G1 = q0_1[0] + __builtin_fmaf(wih0_1, yv, bias0_1);
        float G2 = q0_2[0] + __builtin_fmaf(wih0_2, yv, bias0_2);
        float G3 = q0_3[0] + __builtin_fmaf(wih0_3, yv, bias0_3);
        float si = sigm(G0), sf = sigm(G1), so = sigm(G3);
        float tg = tanh_f(G2);
        c0v = __builtin_fmaf(sf, c0v, si * tg);
        float h0nv = so * tanh_f(c0v);
        if (ln < 16) hsm[(p ^ 1) * 128 + ev] = (h16)h0nv;
        __syncthreads();  // B1: h0_out(s) ready

        // ---- periodic output flush (uniform, 1/192 steps) ----
        if (s == flush_at) {
            if (t < YRING) outb[flush_at - YRING + t] = ybuf[t];
            flush_at += YRING;
        }

        // ---- phase B: Wih1 @ h0_out(s) into q1; Whh0 @ h0_out(s) into q0
        //      (q0 = gates0 pre-work for step s+1, same A-operands) ----
        const int hb = 8 * grp + (p ^ 1) * 128;
        h16x8 d0 = *(const h16x8*)&hsm[hb + 0];
        h16x8 d1 = *(const h16x8*)&hsm[hb + 32];
        h16x8 d2 = *(const h16x8*)&hsm[hb + 64];
        h16x8 d3 = *(const h16x8*)&hsm[hb + 96];
        CHAIN_CONT(q1_0, 1, 0, d0, d1, d2, d3)
        CHAIN_CONT(q1_1, 1, 1, d0, d1, d2, d3)
        CHAIN_CONT(q1_2, 1, 2, d0, d1, d2, d3)
        CHAIN_CONT(q1_3, 1, 3, d0, d1, d2, d3)
        CHAIN(q0_0, 0, 0, d0, d1, d2, d3)
        CHAIN(q0_1, 0, 1, d0, d1, d2, d3)
        CHAIN(q0_2, 0, 2, d0, d1, d2, d3)
        CHAIN(q0_3, 0, 3, d0, d1, d2, d3)

        // ---- act1 + fc (VALU overlaps q0 chain issue) ----
        float H0 = q1_0[0] + bias1_0;
        float H1 = q1_1[0] + bias1_1;
        float H2 = q1_2[0] + bias1_2;
        float H3 = q1_3[0] + bias1_3;
        float ti = sigm(H0), tf = sigm(H1), to = sigm(H3);
        float tgg = tanh_f(H2);
        c1v = __builtin_fmaf(tf, c1v, ti * tgg);
        float h1nv = to * tanh_f(c1v);
        if (ln < 16) hsm[256 + (p ^ 1) * 128 + ev] = (h16)h1nv;

        float part = sum16(fcw_e * h1nv);
        if (ln == 0) ypartbuf[wv] = part;
        __syncthreads();  // B2: h1_out(s) + ypart ready

        // ---- y(s): assembled by every lane, carried to next iteration ----
        yv = sum8(ypartbuf[ln & 7]) + fcb_;
        if (t == 0) ybuf[ys] = yv;
        ys = (ys == YRING - 1) ? 0 : ys + 1;

        p ^= 1;
    }

    // ---- epilogue: final window flush (ybuf written pre-barrier) ----
    __syncthreads();
    if (t < YRING) outb[HSTEPS - YRING + t] = ybuf[t];
}

extern "C" void kernel_launch(void* const* d_in, const int* in_sizes, int n_in,
                              void* d_out, int out_size, void* d_ws,
                              size_t ws_size, hipStream_t stream) {
    const float* y0 = (const float*)d_in[0];
    const float* h0 = (const float*)d_in[1];
    const float* c0 = (const float*)d_in[2];
    const float* Wih0 = (const float*)d_in[3];
    const float* Whh0 = (const float*)d_in[4];
    const float* bih0 = (const float*)d_in[5];
    const float* bhh0 = (const float*)d_in[6];
    const float* Wih1 = (const float*)d_in[7];
    const float* Whh1 = (const float*)d_in[8];
    const float* bih1 = (const float*)d_in[9];
    const float* bhh1 = (const float*)d_in[10];
    const float* fcw = (const float*)d_in[11];
    const float* fcb = (const float*)d_in[12];
    float* out = (float*)d_out;

    lstm2_kernel<<<dim3(BATCH), dim3(NTHR), 0, stream>>>(
        y0, h0, c0, Wih0, Whh0, bih0, bhh0, Wih1, Whh1, bih1, bhh1, fcw, fcb,
        out);
}

// Round 10
// 8576.842 us; speedup vs baseline: 1.5488x; 1.2463x over previous
//
#include <hip/hip_runtime.h>

#define HSTEPS 8640
#define HID 128
#define BATCH 16
#define NTHR 512
#define YRING 192
#define INV127 (1.0f / 127.0f)

typedef __attribute__((ext_vector_type(4))) int i32x4;

static __device__ __forceinline__ float sigm(float x) {
    return __builtin_amdgcn_rcpf(1.0f + __expf(-x));
}
static __device__ __forceinline__ float tanh_f(float x) {
    float ax = __builtin_fabsf(x);
    float ee = __expf(2.0f * ax);
    float r = 1.0f - 2.0f * __builtin_amdgcn_rcpf(ee + 1.0f);
    return __builtin_copysignf(r, x);
}
template <int CTRL>
static __device__ __forceinline__ float dppmov(float x) {
    return __int_as_float(
        __builtin_amdgcn_mov_dpp(__float_as_int(x), CTRL, 0xF, 0xF, false));
}
static __device__ __forceinline__ float sum8(float x) {
    x += dppmov<0x121>(x);
    x += dppmov<0x122>(x);
    x += dppmov<0x124>(x);
    return x;
}
static __device__ __forceinline__ float sum16(float x) {
    x += dppmov<0x121>(x);
    x += dppmov<0x122>(x);
    x += dppmov<0x124>(x);
    x += dppmov<0x128>(x);
    return x;
}
static __device__ __forceinline__ float max16(float x) {
    x = fmaxf(x, dppmov<0x121>(x));
    x = fmaxf(x, dppmov<0x122>(x));
    x = fmaxf(x, dppmov<0x124>(x));
    x = fmaxf(x, dppmov<0x128>(x));
    return x;
}
// lane^16 exchange via ds_swizzle BitMode (xor=16)
static __device__ __forceinline__ float swzx16(float x) {
    return __int_as_float(
        __builtin_amdgcn_ds_swizzle(__float_as_int(x), 0x401F));
}

static __device__ __forceinline__ int pack4(const float* v, float inv) {
    int a = (int)__builtin_rintf(v[0] * inv);
    int b = (int)__builtin_rintf(v[1] * inv);
    int c = (int)__builtin_rintf(v[2] * inv);
    int d = (int)__builtin_rintf(v[3] * inv);
    return (a & 0xff) | ((b & 0xff) << 8) | ((c & 0xff) << 16) |
           ((d & 0xff) << 24);
}

// Quantize this lane's K-slices of one gate row to i8 with a per-row scale.
// Row spans 4 grp-lanes x 32 cols each; rowmax reduced via lane^16 + lane^32.
static __device__ __forceinline__ void quantrow(const float* rp, int grp,
                                                i32x4& f0, i32x4& f1,
                                                float& sw) {
    float v[32];
#pragma unroll
    for (int j = 0; j < 16; ++j) v[j] = rp[16 * grp + j];
#pragma unroll
    for (int j = 0; j < 16; ++j) v[16 + j] = rp[64 + 16 * grp + j];
    float mx = 1e-20f;
#pragma unroll
    for (int j = 0; j < 32; ++j) mx = fmaxf(mx, __builtin_fabsf(v[j]));
    mx = fmaxf(mx, swzx16(mx));
    mx = fmaxf(mx, __shfl_xor(mx, 32, 64));
    float inv = 127.0f / mx;
    sw = mx * INV127;
    f0 = i32x4{pack4(v, inv), pack4(v + 4, inv), pack4(v + 8, inv),
               pack4(v + 12, inv)};
    f1 = i32x4{pack4(v + 16, inv), pack4(v + 20, inv), pack4(v + 24, inv),
               pack4(v + 28, inv)};
}

// ---- weight fragments: 24 named i32x4 (96 regs) + 12 row-scale floats ----
#define FRAGS(F) \
    F(0, 0) F(0, 1) F(0, 2) F(0, 3) \
    F(1, 0) F(1, 1) F(1, 2) F(1, 3) \
    F(2, 0) F(2, 1) F(2, 2) F(2, 3)
#define DECLF(m, g) i32x4 wq##m##_##g##_0, wq##m##_##g##_1; float sw##m##_##g;
#define WPTR0 Whh0
#define WPTR1 Wih1
#define WPTR2 Whh1
#define QROW(m, g)                                                          \
    quantrow(WPTR##m + (size_t)(128 * g + 16 * wv + ln15) * HID, grp,       \
             wq##m##_##g##_0, wq##m##_##g##_1, sw##m##_##g);

// K=64 chain: 2 chunked MFMAs per gate tile (acc starts from zero)
#define CHAIN2(q, A0, A1, m, g)                                             \
    q = __builtin_amdgcn_mfma_i32_16x16x64_i8((A0), wq##m##_##g##_0, zqi, 0, \
                                              0, 0);                         \
    q = __builtin_amdgcn_mfma_i32_16x16x64_i8((A1), wq##m##_##g##_1, (q), 0, \
                                              0, 0);

// One block per batch; 512 threads = 8 waves, 2/SIMD. Weights quantized to
// i8 on device (per-row f32 scale), held in 96 regs/lane as MFMA-B frags.
// h quantized to i8 (scale 1/127; prologue scale for the unbounded initial
// h). mfma_i32_16x16x64_i8 halves the per-step MFMA pipe cycles vs f16.
__global__ __launch_bounds__(NTHR, 2) void lstm2_kernel(
    const float* __restrict__ y0, const float* __restrict__ h0in,
    const float* __restrict__ c0in, const float* __restrict__ Wih0,
    const float* __restrict__ Whh0, const float* __restrict__ bih0,
    const float* __restrict__ bhh0, const float* __restrict__ Wih1,
    const float* __restrict__ Whh1, const float* __restrict__ bih1,
    const float* __restrict__ bhh1, const float* __restrict__ fcw,
    const float* __restrict__ fcb, float* __restrict__ out) {
    const int b = blockIdx.x;
    const int t = threadIdx.x;
    const int wv = t >> 6;     // wave 0..7
    const int ln = t & 63;     // lane
    const int grp = ln >> 4;   // k-slot 0..3 (16 bytes each)
    const int ln15 = ln & 15;  // B col / element-within-wave
    const int ev = 16 * wv + ln15;  // this lane's element 0..127

    // hsm8 (bytes): [0..127]=h0 buf0, [128..255]=h0 buf1,
    //               [256..383]=h1 buf0, [384..511]=h1 buf1
    __shared__ __align__(16) char hsm8[512];
    __shared__ float ypartbuf[8];
    __shared__ float maxb[16];
    __shared__ float ybuf[YRING];

    FRAGS(DECLF)
    FRAGS(QROW)

    const float bias0_0 = bih0[ev] + bhh0[ev];
    const float bias0_1 = bih0[128 + ev] + bhh0[128 + ev];
    const float bias0_2 = bih0[256 + ev] + bhh0[256 + ev];
    const float bias0_3 = bih0[384 + ev] + bhh0[384 + ev];
    const float bias1_0 = bih1[ev] + bhh1[ev];
    const float bias1_1 = bih1[128 + ev] + bhh1[128 + ev];
    const float bias1_2 = bih1[256 + ev] + bhh1[256 + ev];
    const float bias1_3 = bih1[384 + ev] + bhh1[384 + ev];
    const float wih0_0 = Wih0[ev];
    const float wih0_1 = Wih0[128 + ev];
    const float wih0_2 = Wih0[256 + ev];
    const float wih0_3 = Wih0[384 + ev];
    const float fcb_ = fcb[0];
    const float fcw_e = fcw[ev];

    float c0v = c0in[b * HID + ev];            // replicated across k-groups
    float c1v = c0in[(BATCH + b) * HID + ev];  // replicated across k-groups

    // ---- prologue: stage initial h with dynamic scales (h unbounded) ----
    float h0f = 0.f, h1f = 0.f;
    if (ln < 16) {
        h0f = h0in[b * HID + ev];
        h1f = h0in[(BATCH + b) * HID + ev];
    }
    float m0 = max16(__builtin_fabsf(h0f));
    float m1 = max16(__builtin_fabsf(h1f));
    if (ln == 0) {
        maxb[wv] = m0;
        maxb[8 + wv] = m1;
    }
    if (t < 8) ypartbuf[t] = (t == 0) ? (y0[b] - fcb_) : 0.0f;
    __syncthreads();
    float bm0 = 1e-20f, bm1 = 1e-20f;
#pragma unroll
    for (int i = 0; i < 8; ++i) {
        bm0 = fmaxf(bm0, maxb[i]);
        bm1 = fmaxf(bm1, maxb[8 + i]);
    }
    const float sh0i = bm0 * INV127;  // initial h0 quant scale
    const float sh1i = bm1 * INV127;  // initial h1 quant scale
    if (ln < 16) {
        hsm8[ev] = (char)(int)__builtin_rintf(h0f * (127.0f / bm0));
        hsm8[256 + ev] = (char)(int)__builtin_rintf(h1f * (127.0f / bm1));
    }
    __syncthreads();

    const i32x4 zqi = {0, 0, 0, 0};
    float* outb = out + (size_t)b * HSTEPS;

    // ---- prologue: q0 = Whh0 @ h0_in(0) (rotation pre-work) ----
    float yv = y0[b];
    float sh_q0 = sh0i;   // h-scale baked into current q0
    float sh_q1b = sh1i;  // h-scale for current Whh1@h1 product
    i32x4 q0_0, q0_1, q0_2, q0_3;
    {
        const char* ap = hsm8 + 16 * grp;
        i32x4 a0 = *(const i32x4*)(ap);
        i32x4 a1 = *(const i32x4*)(ap + 64);
        CHAIN2(q0_0, a0, a1, 0, 0)
        CHAIN2(q0_1, a0, a1, 0, 1)
        CHAIN2(q0_2, a0, a1, 0, 2)
        CHAIN2(q0_3, a0, a1, 0, 3)
    }

    int p = 0;
    int ys = 0;
    int flush_at = YRING;

#pragma unroll 1
    for (int s = 0; s < HSTEPS; ++s) {
        // ---- phase A: qb = Whh1 @ h1_in(s) (independent of act0) ----
        const char* h1p = hsm8 + 256 + 128 * p + 16 * grp;
        i32x4 b0 = *(const i32x4*)(h1p);
        i32x4 b1 = *(const i32x4*)(h1p + 64);
        i32x4 qb0, qb1, qb2, qb3;
        CHAIN2(qb0, b0, b1, 2, 0)
        CHAIN2(qb1, b0, b1, 2, 1)
        CHAIN2(qb2, b0, b1, 2, 2)
        CHAIN2(qb3, b0, b1, 2, 3)

        // ---- act0: q0 from previous iteration (long drained) ----
        float G0 = __builtin_fmaf(sw0_0 * sh_q0, (float)q0_0[0],
                                  __builtin_fmaf(wih0_0, yv, bias0_0));
        float G1 = __builtin_fmaf(sw0_1 * sh_q0, (float)q0_1[0],
                                  __builtin_fmaf(wih0_1, yv, bias0_1));
        float G2 = __builtin_fmaf(sw0_2 * sh_q0, (float)q0_2[0],
                                  __builtin_fmaf(wih0_2, yv, bias0_2));
        float G3 = __builtin_fmaf(sw0_3 * sh_q0, (float)q0_3[0],
                                  __builtin_fmaf(wih0_3, yv, bias0_3));
        sh_q0 = INV127;  // all later q0 come from tanh-bounded h0n
        float si = sigm(G0), sf = sigm(G1), so = sigm(G3);
        float tg = tanh_f(G2);
        c0v = __builtin_fmaf(sf, c0v, si * tg);
        float h0nv = so * tanh_f(c0v);
        if (ln < 16)
            hsm8[(p ^ 1) * 128 + ev] =
                (char)(int)__builtin_rintf(h0nv * 127.0f);
        __syncthreads();  // B1: h0_out(s) ready

        // ---- periodic output flush (uniform, 1/192 steps) ----
        if (s == flush_at) {
            if (t < YRING) outb[flush_at - YRING + t] = ybuf[t];
            flush_at += YRING;
        }

        // ---- phase B: qa = Wih1 @ h0n ; q0 = Whh0 @ h0n (step s+1) ----
        const char* h0np = hsm8 + (p ^ 1) * 128 + 16 * grp;
        i32x4 d0 = *(const i32x4*)(h0np);
        i32x4 d1 = *(const i32x4*)(h0np + 64);
        i32x4 qa0, qa1, qa2, qa3;
        CHAIN2(qa0, d0, d1, 1, 0)
        CHAIN2(qa1, d0, d1, 1, 1)
        CHAIN2(qa2, d0, d1, 1, 2)
        CHAIN2(qa3, d0, d1, 1, 3)
        CHAIN2(q0_0, d0, d1, 0, 0)
        CHAIN2(q0_1, d0, d1, 0, 1)
        CHAIN2(q0_2, d0, d1, 0, 2)
        CHAIN2(q0_3, d0, d1, 0, 3)

        // ---- act1: two scaled dots + bias ----
        float H0 = __builtin_fmaf(
            sw1_0 * INV127, (float)qa0[0],
            __builtin_fmaf(sw2_0 * sh_q1b, (float)qb0[0], bias1_0));
        float H1 = __builtin_fmaf(
            sw1_1 * INV127, (float)qa1[0],
            __builtin_fmaf(sw2_1 * sh_q1b, (float)qb1[0], bias1_1));
        float H2 = __builtin_fmaf(
            sw1_2 * INV127, (float)qa2[0],
            __builtin_fmaf(sw2_2 * sh_q1b, (float)qb2[0], bias1_2));
        float H3 = __builtin_fmaf(
            sw1_3 * INV127, (float)qa3[0],
            __builtin_fmaf(sw2_3 * sh_q1b, (float)qb3[0], bias1_3));
        sh_q1b = INV127;
        float ti = sigm(H0), tf = sigm(H1), to = sigm(H3);
        float tgg = tanh_f(H2);
        c1v = __builtin_fmaf(tf, c1v, ti * tgg);
        float h1nv = to * tanh_f(c1v);
        if (ln < 16)
            hsm8[256 + (p ^ 1) * 128 + ev] =
                (char)(int)__builtin_rintf(h1nv * 127.0f);

        // ---- fused fc on full-precision h1 ----
        float part = sum16(fcw_e * h1nv);
        if (ln == 0) ypartbuf[wv] = part;
        __syncthreads();  // B2: h1_out(s) + ypart ready

        // ---- y(s): assembled by every lane, carried to next iteration ----
        yv = sum8(ypartbuf[ln & 7]) + fcb_;
        if (t == 0) ybuf[ys] = yv;
        ys = (ys == YRING - 1) ? 0 : ys + 1;

        p ^= 1;
    }

    // ---- epilogue: final window flush ----
    __syncthreads();
    if (t < YRING) outb[HSTEPS - YRING + t] = ybuf[t];
}

extern "C" void kernel_launch(void* const* d_in, const int* in_sizes, int n_in,
                              void* d_out, int out_size, void* d_ws,
                              size_t ws_size, hipStream_t stream) {
    const float* y0 = (const float*)d_in[0];
    const float* h0 = (const float*)d_in[1];
    const float* c0 = (const float*)d_in[2];
    const float* Wih0 = (const float*)d_in[3];
    const float* Whh0 = (const float*)d_in[4];
    const float* bih0 = (const float*)d_in[5];
    const float* bhh0 = (const float*)d_in[6];
    const float* Wih1 = (const float*)d_in[7];
    const float* Whh1 = (const float*)d_in[8];
    const float* bih1 = (const float*)d_in[9];
    const float* bhh1 = (const float*)d_in[10];
    const float* fcw = (const float*)d_in[11];
    const float* fcb = (const float*)d_in[12];
    float* out = (float*)d_out;

    lstm2_kernel<<<dim3(BATCH), dim3(NTHR), 0, stream>>>(
        y0, h0, c0, Wih0, Whh0, bih0, bhh0, Wih1, Whh1, bih1, bhh1, fcw, fcb,
        out);
}

// Round 11
// 7984.158 us; speedup vs baseline: 1.6637x; 1.0742x over previous
//
#include <hip/hip_runtime.h>

#define HSTEPS 8640
#define HID 128
#define BATCH 16
#define NTHR 512
#define YRING 192
#define INV127 (1.0f / 127.0f)

typedef __attribute__((ext_vector_type(4))) int i32x4;

static __device__ __forceinline__ float sigm(float x) {
    return __builtin_amdgcn_rcpf(1.0f + __expf(-x));
}
static __device__ __forceinline__ float tanh_f(float x) {
    float ax = __builtin_fabsf(x);
    float ee = __expf(2.0f * ax);
    float r = 1.0f - 2.0f * __builtin_amdgcn_rcpf(ee + 1.0f);
    return __builtin_copysignf(r, x);
}
template <int CTRL>
static __device__ __forceinline__ float dppmov(float x) {
    return __int_as_float(
        __builtin_amdgcn_mov_dpp(__float_as_int(x), CTRL, 0xF, 0xF, false));
}
// sum of 4-periodic values -> every lane holds its 4-group total
static __device__ __forceinline__ float sum4(float x) {
    x += dppmov<0x121>(x);
    x += dppmov<0x122>(x);
    return x;
}
// sum across each 16-lane row -> every lane holds its row's sum
static __device__ __forceinline__ float sum16(float x) {
    x += dppmov<0x121>(x);
    x += dppmov<0x122>(x);
    x += dppmov<0x124>(x);
    x += dppmov<0x128>(x);
    return x;
}
// wave64 max (values >= 0) -> lane 63 holds the wave max
static __device__ __forceinline__ float maxwave(float x) {
    x = fmaxf(x, dppmov<0x121>(x));
    x = fmaxf(x, dppmov<0x122>(x));
    x = fmaxf(x, dppmov<0x124>(x));
    x = fmaxf(x, dppmov<0x128>(x));
    float t1 = __int_as_float(__builtin_amdgcn_update_dpp(
        0, __float_as_int(x), 0x142, 0xA, 0xF, false));
    x = fmaxf(x, t1);
    float t2 = __int_as_float(__builtin_amdgcn_update_dpp(
        0, __float_as_int(x), 0x143, 0xC, 0xF, false));
    x = fmaxf(x, t2);
    return x;
}
// lane^16 exchange via ds_swizzle BitMode
static __device__ __forceinline__ float swzx16(float x) {
    return __int_as_float(
        __builtin_amdgcn_ds_swizzle(__float_as_int(x), 0x401F));
}

static __device__ __forceinline__ int pack4(const float* v, float inv) {
    int a = (int)__builtin_rintf(v[0] * inv);
    int b = (int)__builtin_rintf(v[1] * inv);
    int c = (int)__builtin_rintf(v[2] * inv);
    int d = (int)__builtin_rintf(v[3] * inv);
    return (a & 0xff) | ((b & 0xff) << 8) | ((c & 0xff) << 16) |
           ((d & 0xff) << 24);
}

// Quantize this lane's K-slices of one gate row to i8 with a per-row scale.
static __device__ __forceinline__ void quantrow(const float* rp, int grp,
                                                i32x4& f0, i32x4& f1,
                                                float& sw) {
    float v[32];
#pragma unroll
    for (int j = 0; j < 16; ++j) v[j] = rp[16 * grp + j];
#pragma unroll
    for (int j = 0; j < 16; ++j) v[16 + j] = rp[64 + 16 * grp + j];
    float mx = 1e-20f;
#pragma unroll
    for (int j = 0; j < 32; ++j) mx = fmaxf(mx, __builtin_fabsf(v[j]));
    mx = fmaxf(mx, swzx16(mx));
    mx = fmaxf(mx, __shfl_xor(mx, 32, 64));
    float inv = 127.0f / mx;
    sw = mx * INV127;
    f0 = i32x4{pack4(v, inv), pack4(v + 4, inv), pack4(v + 8, inv),
               pack4(v + 12, inv)};
    f1 = i32x4{pack4(v + 16, inv), pack4(v + 20, inv), pack4(v + 24, inv),
               pack4(v + 28, inv)};
}

// in-lane LSTM activation (gates i,f,g,o), updates c, returns h
static __device__ __forceinline__ float act_upd(float gi, float gf, float gg,
                                                float go, float& c) {
    float si = sigm(gi), sf = sigm(gf), so = sigm(go);
    float tg = tanh_f(gg);
    c = __builtin_fmaf(sf, c, si * tg);
    return so * tanh_f(c);
}

// tile T = g*2+j : rows 128*g + 16*(2*gw+j) + ln15
#define LOADT(M, T, FA, FB, SS)                                               \
    quantrow((M) + (size_t)(128 * ((T) >> 1) + 16 * (2 * gw + ((T) & 1)) +    \
                            ln15) * HID,                                      \
             grp, FA, FB, SS);

#define CH2(Q, A0, A1, FA, FB)                                                \
    Q = __builtin_amdgcn_mfma_i32_16x16x64_i8((A0), FA, zqi, 0, 0, 0);        \
    Q = __builtin_amdgcn_mfma_i32_16x16x64_i8((A1), FB, (Q), 0, 0, 0);

// Wave-role-specialized: waves 0-3 (X) own layer 0 (Whh0, act0); waves 4-7
// (Y) own layer 1 (Wih1+Whh1, act1+fc). One block per batch, 8 waves,
// 2/SIMD: each SIMD pairs one X-wave with one Y-wave so acts/latency of one
// role hide under MFMA issue of the other. i8 weights (per-row scales), h in
// i8 via LDS. Whh0 for step s+1 issues in half 2 of step s (rotation).
__global__ __launch_bounds__(NTHR, 2) void lstm2_kernel(
    const float* __restrict__ y0, const float* __restrict__ h0in,
    const float* __restrict__ c0in, const float* __restrict__ Wih0,
    const float* __restrict__ Whh0, const float* __restrict__ bih0,
    const float* __restrict__ bhh0, const float* __restrict__ Wih1,
    const float* __restrict__ Whh1, const float* __restrict__ bih1,
    const float* __restrict__ bhh1, const float* __restrict__ fcw,
    const float* __restrict__ fcb, float* __restrict__ out) {
    const int b = blockIdx.x;
    const int t = threadIdx.x;
    const int wv = t >> 6;
    const int ln = t & 63;
    const int grp = ln >> 4;
    const int ln15 = ln & 15;
    const int gw = wv & 3;  // index within role group
    const bool isX = wv < 4;
    const int e0 = 32 * gw + ln15;  // first owned element
    const int e1 = e0 + 16;         // second owned element

    // hsm8 bytes: [0..127]=h0 buf0, [128..255]=h0 buf1,
    //             [256..383]=h1 buf0, [384..511]=h1 buf1
    __shared__ __align__(16) char hsm8[512];
    __shared__ float ypartbuf[4];
    __shared__ float maxb[8];
    __shared__ float ybuf[YRING];

    const i32x4 zqi = {0, 0, 0, 0};

    // ---- shared register pool (per-thread meaning depends on role) ----
    i32x4 Fq0 = zqi, Fq1 = zqi, Fq2 = zqi, Fq3 = zqi, Fq4 = zqi, Fq5 = zqi,
          Fq6 = zqi, Fq7 = zqi, Fq8 = zqi, Fq9 = zqi, Fq10 = zqi, Fq11 = zqi,
          Fq12 = zqi, Fq13 = zqi, Fq14 = zqi, Fq15 = zqi, Fq16 = zqi,
          Fq17 = zqi, Fq18 = zqi, Fq19 = zqi, Fq20 = zqi, Fq21 = zqi,
          Fq22 = zqi, Fq23 = zqi, Fq24 = zqi, Fq25 = zqi, Fq26 = zqi,
          Fq27 = zqi, Fq28 = zqi, Fq29 = zqi, Fq30 = zqi, Fq31 = zqi;
    float S0 = 0, S1 = 0, S2 = 0, S3 = 0, S4 = 0, S5 = 0, S6 = 0, S7 = 0,
          S8 = 0, S9 = 0, S10 = 0, S11 = 0, S12 = 0, S13 = 0, S14 = 0,
          S15 = 0;
    i32x4 QA0 = zqi, QA1 = zqi, QA2 = zqi, QA3 = zqi, QA4 = zqi, QA5 = zqi,
          QA6 = zqi, QA7 = zqi;
    i32x4 QB0 = zqi, QB1 = zqi, QB2 = zqi, QB3 = zqi, QB4 = zqi, QB5 = zqi,
          QB6 = zqi, QB7 = zqi;
    float B0 = 0, B1 = 0, B2 = 0, B3 = 0, B4 = 0, B5 = 0, B6 = 0, B7 = 0;
    float E0 = 0, E1 = 0, E2 = 0, E3 = 0, E4 = 0, E5 = 0, E6 = 0, E7 = 0;
    float C0, C1;

    if (isX) {  // X: Whh0 fragments, bias0, Wih0 column, c0
        LOADT(Whh0, 0, Fq0, Fq1, S0) LOADT(Whh0, 1, Fq2, Fq3, S1)
        LOADT(Whh0, 2, Fq4, Fq5, S2) LOADT(Whh0, 3, Fq6, Fq7, S3)
        LOADT(Whh0, 4, Fq8, Fq9, S4) LOADT(Whh0, 5, Fq10, Fq11, S5)
        LOADT(Whh0, 6, Fq12, Fq13, S6) LOADT(Whh0, 7, Fq14, Fq15, S7)
        B0 = bih0[e0] + bhh0[e0];
        B1 = bih0[e1] + bhh0[e1];
        B2 = bih0[128 + e0] + bhh0[128 + e0];
        B3 = bih0[128 + e1] + bhh0[128 + e1];
        B4 = bih0[256 + e0] + bhh0[256 + e0];
        B5 = bih0[256 + e1] + bhh0[256 + e1];
        B6 = bih0[384 + e0] + bhh0[384 + e0];
        B7 = bih0[384 + e1] + bhh0[384 + e1];
        E0 = Wih0[e0];
        E1 = Wih0[e1];
        E2 = Wih0[128 + e0];
        E3 = Wih0[128 + e1];
        E4 = Wih0[256 + e0];
        E5 = Wih0[256 + e1];
        E6 = Wih0[384 + e0];
        E7 = Wih0[384 + e1];
        C0 = c0in[b * HID + e0];
        C1 = c0in[b * HID + e1];
    } else {  // Y: Wih1 -> Fq0..15/S0..7, Whh1 -> Fq16..31/S8..15
        LOADT(Wih1, 0, Fq0, Fq1, S0) LOADT(Wih1, 1, Fq2, Fq3, S1)
        LOADT(Wih1, 2, Fq4, Fq5, S2) LOADT(Wih1, 3, Fq6, Fq7, S3)
        LOADT(Wih1, 4, Fq8, Fq9, S4) LOADT(Wih1, 5, Fq10, Fq11, S5)
        LOADT(Wih1, 6, Fq12, Fq13, S6) LOADT(Wih1, 7, Fq14, Fq15, S7)
        LOADT(Whh1, 0, Fq16, Fq17, S8) LOADT(Whh1, 1, Fq18, Fq19, S9)
        LOADT(Whh1, 2, Fq20, Fq21, S10) LOADT(Whh1, 3, Fq22, Fq23, S11)
        LOADT(Whh1, 4, Fq24, Fq25, S12) LOADT(Whh1, 5, Fq26, Fq27, S13)
        LOADT(Whh1, 6, Fq28, Fq29, S14) LOADT(Whh1, 7, Fq30, Fq31, S15)
        // qa operand h0n is always tanh-bounded: fold 1/127 into S0..7
        S0 *= INV127; S1 *= INV127; S2 *= INV127; S3 *= INV127;
        S4 *= INV127; S5 *= INV127; S6 *= INV127; S7 *= INV127;
        B0 = bih1[e0] + bhh1[e0];
        B1 = bih1[e1] + bhh1[e1];
        B2 = bih1[128 + e0] + bhh1[128 + e0];
        B3 = bih1[128 + e1] + bhh1[128 + e1];
        B4 = bih1[256 + e0] + bhh1[256 + e0];
        B5 = bih1[256 + e1] + bhh1[256 + e1];
        B6 = bih1[384 + e0] + bhh1[384 + e0];
        B7 = bih1[384 + e1] + bhh1[384 + e1];
        E0 = fcw[e0];
        E1 = fcw[e1];
        C0 = c0in[(BATCH + b) * HID + e0];
        C1 = c0in[(BATCH + b) * HID + e1];
    }

    const float fcb_ = fcb[0];

    // ---- prologue: stage initial h (dynamic block scales) ----
    float hv_ = 0.f;
    if (t < 128) hv_ = h0in[b * HID + t];
    else if (t < 256) hv_ = h0in[(BATCH + b) * HID + (t - 128)];
    float am = maxwave(__builtin_fabsf(hv_));
    if (ln == 63) maxb[wv] = am;
    if (t < 4) ypartbuf[t] = (t == 0) ? (y0[b] - fcb_) : 0.0f;
    __syncthreads();
    const float bm0 = fmaxf(fmaxf(maxb[0], maxb[1]), 1e-20f);
    const float bm1 = fmaxf(fmaxf(maxb[2], maxb[3]), 1e-20f);
    if (t < 128)
        hsm8[t] = (char)(int)__builtin_rintf(hv_ * (127.0f / bm0));
    else if (t < 256)
        hsm8[256 + (t - 128)] = (char)(int)__builtin_rintf(hv_ * (127.0f / bm1));
    __syncthreads();

    // h-scale for the role's first accumulated product, then 1/127
    float shq = isX ? (bm0 * INV127) : (bm1 * INV127);

    float* outb = out + (size_t)b * HSTEPS;

    // ---- X preamble: QA = Whh0 @ h0_in(0) ----
    if (isX) {
        i32x4 a0 = *(const i32x4*)&hsm8[16 * grp];
        i32x4 a1 = *(const i32x4*)&hsm8[64 + 16 * grp];
        CH2(QA0, a0, a1, Fq0, Fq1) CH2(QA1, a0, a1, Fq2, Fq3)
        CH2(QA2, a0, a1, Fq4, Fq5) CH2(QA3, a0, a1, Fq6, Fq7)
        CH2(QA4, a0, a1, Fq8, Fq9) CH2(QA5, a0, a1, Fq10, Fq11)
        CH2(QA6, a0, a1, Fq12, Fq13) CH2(QA7, a0, a1, Fq14, Fq15)
    }

    int p = 0;
    int ys = 0;
    int flush_at = YRING;

#pragma unroll 1
    for (int s = 0; s < HSTEPS; ++s) {
        // ================= half 1 =================
        if (isX) {
            // y(s-1) from Y's partials; act0(s); publish h0_out(s)
            float yv = sum4(ypartbuf[ln & 3]) + fcb_;
            if (s > 0) {
                if (t == 0) ybuf[ys] = yv;
                ys = (ys == YRING - 1) ? 0 : ys + 1;
            }
            float G0 = __builtin_fmaf(S0 * shq, (float)QA0[0],
                                      __builtin_fmaf(E0, yv, B0));
            float G1 = __builtin_fmaf(S2 * shq, (float)QA2[0],
                                      __builtin_fmaf(E2, yv, B2));
            float G2 = __builtin_fmaf(S4 * shq, (float)QA4[0],
                                      __builtin_fmaf(E4, yv, B4));
            float G3 = __builtin_fmaf(S6 * shq, (float)QA6[0],
                                      __builtin_fmaf(E6, yv, B6));
            float h0a = act_upd(G0, G1, G2, G3, C0);
            G0 = __builtin_fmaf(S1 * shq, (float)QA1[0],
                                __builtin_fmaf(E1, yv, B1));
            G1 = __builtin_fmaf(S3 * shq, (float)QA3[0],
                                __builtin_fmaf(E3, yv, B3));
            G2 = __builtin_fmaf(S5 * shq, (float)QA5[0],
                                __builtin_fmaf(E5, yv, B5));
            G3 = __builtin_fmaf(S7 * shq, (float)QA7[0],
                                __builtin_fmaf(E7, yv, B7));
            float h0b = act_upd(G0, G1, G2, G3, C1);
            if (ln < 16) {
                hsm8[(p ^ 1) * 128 + e0] =
                    (char)(int)__builtin_rintf(h0a * 127.0f);
                hsm8[(p ^ 1) * 128 + e1] =
                    (char)(int)__builtin_rintf(h0b * 127.0f);
            }
            shq = INV127;
        } else {
            // QB = Whh1 @ h1_in(s) (no dependency on act0)
            const char* h1p = hsm8 + 256 + 128 * p + 16 * grp;
            i32x4 b0_ = *(const i32x4*)(h1p);
            i32x4 b1_ = *(const i32x4*)(h1p + 64);
            CH2(QB0, b0_, b1_, Fq16, Fq17) CH2(QB1, b0_, b1_, Fq18, Fq19)
            CH2(QB2, b0_, b1_, Fq20, Fq21) CH2(QB3, b0_, b1_, Fq22, Fq23)
            CH2(QB4, b0_, b1_, Fq24, Fq25) CH2(QB5, b0_, b1_, Fq26, Fq27)
            CH2(QB6, b0_, b1_, Fq28, Fq29) CH2(QB7, b0_, b1_, Fq30, Fq31)
        }
        __syncthreads();  // B1: h0_out(s) ready

        // ================= half 2 =================
        if (isX) {
            // periodic output flush (X only; t<192 all in X)
            if (s == flush_at) {
                if (t < YRING) outb[flush_at - YRING + t] = ybuf[t];
                flush_at += YRING;
            }
            // QA = Whh0 @ h0_out(s)  (gates0 pre-work for step s+1)
            const char* h0np = hsm8 + (p ^ 1) * 128 + 16 * grp;
            i32x4 d0 = *(const i32x4*)(h0np);
            i32x4 d1 = *(const i32x4*)(h0np + 64);
            CH2(QA0, d0, d1, Fq0, Fq1) CH2(QA1, d0, d1, Fq2, Fq3)
            CH2(QA2, d0, d1, Fq4, Fq5) CH2(QA3, d0, d1, Fq6, Fq7)
            CH2(QA4, d0, d1, Fq8, Fq9) CH2(QA5, d0, d1, Fq10, Fq11)
            CH2(QA6, d0, d1, Fq12, Fq13) CH2(QA7, d0, d1, Fq14, Fq15)
        } else {
            __builtin_amdgcn_s_setprio(1);
            // QA = Wih1 @ h0_out(s); act1; publish h1_out(s), y-partial
            const char* h0np = hsm8 + (p ^ 1) * 128 + 16 * grp;
            i32x4 d0 = *(const i32x4*)(h0np);
            i32x4 d1 = *(const i32x4*)(h0np + 64);
            CH2(QA0, d0, d1, Fq0, Fq1) CH2(QA1, d0, d1, Fq2, Fq3)
            CH2(QA2, d0, d1, Fq4, Fq5) CH2(QA3, d0, d1, Fq6, Fq7)
            CH2(QA4, d0, d1, Fq8, Fq9) CH2(QA5, d0, d1, Fq10, Fq11)
            CH2(QA6, d0, d1, Fq12, Fq13) CH2(QA7, d0, d1, Fq14, Fq15)
            float H0 = __builtin_fmaf(
                S0, (float)QA0[0],
                __builtin_fmaf(S8 * shq, (float)QB0[0], B0));
            float H1 = __builtin_fmaf(
                S2, (float)QA2[0],
                __builtin_fmaf(S10 * shq, (float)QB2[0], B2));
            float H2 = __builtin_fmaf(
                S4, (float)QA4[0],
                __builtin_fmaf(S12 * shq, (float)QB4[0], B4));
            float H3 = __builtin_fmaf(
                S6, (float)QA6[0],
                __builtin_fmaf(S14 * shq, (float)QB6[0], B6));
            float h1a = act_upd(H0, H1, H2, H3, C0);
            H0 = __builtin_fmaf(S1, (float)QA1[0],
                                __builtin_fmaf(S9 * shq, (float)QB1[0], B1));
            H1 = __builtin_fmaf(S3, (float)QA3[0],
                                __builtin_fmaf(S11 * shq, (float)QB3[0], B3));
            H2 = __builtin_fmaf(S5, (float)QA5[0],
                                __builtin_fmaf(S13 * shq, (float)QB5[0], B5));
            H3 = __builtin_fmaf(S7, (float)QA7[0],
                                __builtin_fmaf(S15 * shq, (float)QB7[0], B7));
            float h1b = act_upd(H0, H1, H2, H3, C1);
            __builtin_amdgcn_s_setprio(0);
            if (ln < 16) {
                hsm8[256 + (p ^ 1) * 128 + e0] =
                    (char)(int)__builtin_rintf(h1a * 127.0f);
                hsm8[256 + (p ^ 1) * 128 + e1] =
                    (char)(int)__builtin_rintf(h1b * 127.0f);
            }
            float part = __builtin_fmaf(E0, h1a, E1 * h1b);
            part = sum16(part);
            if (ln == 0) ypartbuf[gw] = part;
            shq = INV127;
        }
        __syncthreads();  // B2: h1_out(s) + ypart ready
        p ^= 1;
    }

    // ---- tail: y(8639) + final flush ----
    if (isX) {
        float yv = sum4(ypartbuf[ln & 3]) + fcb_;
        if (t == 0) ybuf[YRING - 1] = yv;
    }
    __syncthreads();
    if (t < YRING) outb[HSTEPS - YRING + t] = ybuf[t];
}

extern "C" void kernel_launch(void* const* d_in, const int* in_sizes, int n_in,
                              void* d_out, int out_size, void* d_ws,
                              size_t ws_size, hipStream_t stream) {
    const float* y0 = (const float*)d_in[0];
    const float* h0 = (const float*)d_in[1];
    const float* c0 = (const float*)d_in[2];
    const float* Wih0 = (const float*)d_in[3];
    const float* Whh0 = (const float*)d_in[4];
    const float* bih0 = (const float*)d_in[5];
    const float* bhh0 = (const float*)d_in[6];
    const float* Wih1 = (const float*)d_in[7];
    const float* Whh1 = (const float*)d_in[8];
    const float* bih1 = (const float*)d_in[9];
    const float* bhh1 = (const float*)d_in[10];
    const float* fcw = (const float*)d_in[11];
    const float* fcb = (const float*)d_in[12];
    float* out = (float*)d_out;

    lstm2_kernel<<<dim3(BATCH), dim3(NTHR), 0, stream>>>(
        y0, h0, c0, Wih0, Whh0, bih0, bhh0, Wih1, Whh1, bih1, bhh1, fcw, fcb,
        out);
}

// Round 12
// 6603.731 us; speedup vs baseline: 2.0115x; 1.2090x over previous
//
#include <hip/hip_runtime.h>

#define HSTEPS 8640
#define HID 128
#define BATCH 16
#define NTHR 512
#define YRING 192
#define INV127 (1.0f / 127.0f)

typedef __attribute__((ext_vector_type(4))) int i32x4;

static __device__ __forceinline__ float sigm(float x) {
    return __builtin_amdgcn_rcpf(1.0f + __expf(-x));
}
template <int CTRL>
static __device__ __forceinline__ float dppmov(float x) {
    return __int_as_float(
        __builtin_amdgcn_mov_dpp(__float_as_int(x), CTRL, 0xF, 0xF, false));
}
// sum of 4-periodic values -> every lane holds its 4-group total
static __device__ __forceinline__ float sum4(float x) {
    x += dppmov<0x121>(x);
    x += dppmov<0x122>(x);
    return x;
}
// full wave64 sum -> total lands in lane 63
static __device__ __forceinline__ float red_wave(float x) {
    x += dppmov<0x121>(x);
    x += dppmov<0x122>(x);
    x += dppmov<0x124>(x);
    x += dppmov<0x128>(x);
    float t1 = __int_as_float(__builtin_amdgcn_update_dpp(
        0, __float_as_int(x), 0x142 /*row_bcast15*/, 0xA, 0xF, false));
    x += t1;
    float t2 = __int_as_float(__builtin_amdgcn_update_dpp(
        0, __float_as_int(x), 0x143 /*row_bcast31*/, 0xC, 0xF, false));
    x += t2;
    return x;
}
// wave64 max (values >= 0) -> lane 63 holds the wave max
static __device__ __forceinline__ float maxwave(float x) {
    x = fmaxf(x, dppmov<0x121>(x));
    x = fmaxf(x, dppmov<0x122>(x));
    x = fmaxf(x, dppmov<0x124>(x));
    x = fmaxf(x, dppmov<0x128>(x));
    float t1 = __int_as_float(__builtin_amdgcn_update_dpp(
        0, __float_as_int(x), 0x142, 0xA, 0xF, false));
    x = fmaxf(x, t1);
    float t2 = __int_as_float(__builtin_amdgcn_update_dpp(
        0, __float_as_int(x), 0x143, 0xC, 0xF, false));
    x = fmaxf(x, t2);
    return x;
}
// lane^16 exchange via ds_swizzle BitMode
static __device__ __forceinline__ float swzx16(float x) {
    return __int_as_float(
        __builtin_amdgcn_ds_swizzle(__float_as_int(x), 0x401F));
}

static __device__ __forceinline__ int pack4(const float* v, float inv) {
    int a = (int)__builtin_rintf(v[0] * inv);
    int b = (int)__builtin_rintf(v[1] * inv);
    int c = (int)__builtin_rintf(v[2] * inv);
    int d = (int)__builtin_rintf(v[3] * inv);
    return (a & 0xff) | ((b & 0xff) << 8) | ((c & 0xff) << 16) |
           ((d & 0xff) << 24);
}

// Quantize this lane's K-slices of one gate row to i8 with a per-row scale.
static __device__ __forceinline__ void quantrow(const float* rp, int grp,
                                                i32x4& f0, i32x4& f1,
                                                float& sw) {
    float v[32];
#pragma unroll
    for (int j = 0; j < 16; ++j) v[j] = rp[16 * grp + j];
#pragma unroll
    for (int j = 0; j < 16; ++j) v[16 + j] = rp[64 + 16 * grp + j];
    float mx = 1e-20f;
#pragma unroll
    for (int j = 0; j < 32; ++j) mx = fmaxf(mx, __builtin_fabsf(v[j]));
    mx = fmaxf(mx, swzx16(mx));
    mx = fmaxf(mx, __shfl_xor(mx, 32, 64));
    float inv = 127.0f / mx;
    sw = mx * INV127;
    f0 = i32x4{pack4(v, inv), pack4(v + 4, inv), pack4(v + 8, inv),
               pack4(v + 12, inv)};
    f1 = i32x4{pack4(v + 16, inv), pack4(v + 20, inv), pack4(v + 24, inv),
               pack4(v + 28, inv)};
}

// tile T = 2*g + jj : rows 128*g + 16*(2*gw+jj) + ln15
#define LOADT(M, T, FA, FB, SS)                                               \
    quantrow((M) + (size_t)(128 * ((T) >> 1) + 16 * (2 * gw + ((T) & 1)) +    \
                            ln15) * HID,                                      \
             grp, FA, FB, SS);

#define CH2(Q, A0, A1, FA, FB)                                                \
    Q = __builtin_amdgcn_mfma_i32_16x16x64_i8((A0), FA, zqi, 0, 0, 0);        \
    Q = __builtin_amdgcn_mfma_i32_16x16x64_i8((A1), FB, (Q), 0, 0, 0);

// Wave-role split (X=layer0, Y=layer1) + act de-dup + gate-split:
// lane handles ONE element e = 32gw + 16*(ln>>5) + ln15; alpha lanes
// (ln&16==0) evaluate sigm for gates i,f; beta lanes for g(tanh via
// sigm(2x)) and o; exchange via ds_swizzle xor16. All scale products
// hoisted; step-0 h-scale fixed up once. i8 MFMA weights in AGPR frags.
__global__ __launch_bounds__(NTHR, 2) void lstm2_kernel(
    const float* __restrict__ y0, const float* __restrict__ h0in,
    const float* __restrict__ c0in, const float* __restrict__ Wih0,
    const float* __restrict__ Whh0, const float* __restrict__ bih0,
    const float* __restrict__ bhh0, const float* __restrict__ Wih1,
    const float* __restrict__ Whh1, const float* __restrict__ bih1,
    const float* __restrict__ bhh1, const float* __restrict__ fcw,
    const float* __restrict__ fcb, float* __restrict__ out) {
    const int b = blockIdx.x;
    const int t = threadIdx.x;
    const int wv = t >> 6;
    const int ln = t & 63;
    const int grp = ln >> 4;   // MFMA A-operand k-slot
    const int ln15 = ln & 15;  // B col within tile
    const int gw = wv & 3;     // index within role group
    const bool isX = wv < 4;
    const int jj = ln >> 5;               // element sub-tile 0/1
    const bool isBt = (ln & 16) != 0;     // beta lanes: gates g,o
    const int e = 32 * gw + 16 * jj + ln15;  // this lane's element
    const float foldc = isBt ? 2.0f : 1.0f;
    const int g1 = isBt ? 2 : 0;  // first owned gate (i or g)

    // hsm8 bytes: [0..127]=h0 buf0, [128..255]=h0 buf1,
    //             [256..383]=h1 buf0, [384..511]=h1 buf1
    __shared__ __align__(16) char hsm8[512];
    __shared__ float ypartbuf[4];
    __shared__ float maxb[8];
    __shared__ float ybuf[YRING];

    const i32x4 zqi = {0, 0, 0, 0};

    // ---- register pool ----
    i32x4 Fq0 = zqi, Fq1 = zqi, Fq2 = zqi, Fq3 = zqi, Fq4 = zqi, Fq5 = zqi,
          Fq6 = zqi, Fq7 = zqi, Fq8 = zqi, Fq9 = zqi, Fq10 = zqi, Fq11 = zqi,
          Fq12 = zqi, Fq13 = zqi, Fq14 = zqi, Fq15 = zqi, Fq16 = zqi,
          Fq17 = zqi, Fq18 = zqi, Fq19 = zqi, Fq20 = zqi, Fq21 = zqi,
          Fq22 = zqi, Fq23 = zqi, Fq24 = zqi, Fq25 = zqi, Fq26 = zqi,
          Fq27 = zqi, Fq28 = zqi, Fq29 = zqi, Fq30 = zqi, Fq31 = zqi;
    i32x4 QA0 = zqi, QA1 = zqi, QA2 = zqi, QA3 = zqi, QA4 = zqi, QA5 = zqi,
          QA6 = zqi, QA7 = zqi;
    i32x4 QB0 = zqi, QB1 = zqi, QB2 = zqi, QB3 = zqi, QB4 = zqi, QB5 = zqi,
          QB6 = zqi, QB7 = zqi;
    // per-lane loop-invariant coefficients (role-dependent meaning)
    float B1c = 0, B2c = 0;          // biases for owned gates (folded)
    float E1c = 0, E2c = 0;          // X: Wih0 cols (folded); Y: E1c=fcw or 0
    float SAb1 = 0, SAb2 = 0;        // base scales (first matrix)
    float SAq1 = 0, SAq2 = 0;        // live scales (include h-scale)
    float SBb1 = 0, SBb2 = 0;        // Y: Whh1 base scales
    float SBq1 = 0, SBq2 = 0;        // Y: live Whh1 scales
    float Cst = 0;                   // cell state (alpha lanes only)

    if (isX) {
        float S0, S1, S2, S3, S4, S5, S6, S7;
        LOADT(Whh0, 0, Fq0, Fq1, S0) LOADT(Whh0, 1, Fq2, Fq3, S1)
        LOADT(Whh0, 2, Fq4, Fq5, S2) LOADT(Whh0, 3, Fq6, Fq7, S3)
        LOADT(Whh0, 4, Fq8, Fq9, S4) LOADT(Whh0, 5, Fq10, Fq11, S5)
        LOADT(Whh0, 6, Fq12, Fq13, S6) LOADT(Whh0, 7, Fq14, Fq15, S7)
        SAb1 = (isBt ? (jj ? S5 : S4) : (jj ? S1 : S0)) * foldc;
        SAb2 = isBt ? (jj ? S7 : S6) : (jj ? S3 : S2);
        B1c = (bih0[g1 * 128 + e] + bhh0[g1 * 128 + e]) * foldc;
        B2c = bih0[(g1 + 1) * 128 + e] + bhh0[(g1 + 1) * 128 + e];
        E1c = Wih0[g1 * 128 + e] * foldc;
        E2c = Wih0[(g1 + 1) * 128 + e];
        Cst = isBt ? 0.f : c0in[b * HID + e];
    } else {
        float S0, S1, S2, S3, S4, S5, S6, S7, S8, S9, S10, S11, S12, S13,
            S14, S15;
        LOADT(Wih1, 0, Fq0, Fq1, S0) LOADT(Wih1, 1, Fq2, Fq3, S1)
        LOADT(Wih1, 2, Fq4, Fq5, S2) LOADT(Wih1, 3, Fq6, Fq7, S3)
        LOADT(Wih1, 4, Fq8, Fq9, S4) LOADT(Wih1, 5, Fq10, Fq11, S5)
        LOADT(Wih1, 6, Fq12, Fq13, S6) LOADT(Wih1, 7, Fq14, Fq15, S7)
        LOADT(Whh1, 0, Fq16, Fq17, S8) LOADT(Whh1, 1, Fq18, Fq19, S9)
        LOADT(Whh1, 2, Fq20, Fq21, S10) LOADT(Whh1, 3, Fq22, Fq23, S11)
        LOADT(Whh1, 4, Fq24, Fq25, S12) LOADT(Whh1, 5, Fq26, Fq27, S13)
        LOADT(Whh1, 6, Fq28, Fq29, S14) LOADT(Whh1, 7, Fq30, Fq31, S15)
        // Wih1 side: h0n always 1/127-scaled -> fold now (SAq fixed)
        SAq1 = (isBt ? (jj ? S5 : S4) : (jj ? S1 : S0)) * foldc * INV127;
        SAq2 = (isBt ? (jj ? S7 : S6) : (jj ? S3 : S2)) * INV127;
        SBb1 = (isBt ? (jj ? S13 : S12) : (jj ? S9 : S8)) * foldc;
        SBb2 = isBt ? (jj ? S15 : S14) : (jj ? S11 : S10);
        B1c = (bih1[g1 * 128 + e] + bhh1[g1 * 128 + e]) * foldc;
        B2c = bih1[(g1 + 1) * 128 + e] + bhh1[(g1 + 1) * 128 + e];
        E1c = isBt ? 0.f : fcw[e];  // fc weight (alpha lanes only)
        Cst = isBt ? 0.f : c0in[(BATCH + b) * HID + e];
    }

    const float fcb_ = fcb[0];

    // ---- prologue: stage initial h (dynamic block scales) ----
    float hv_ = 0.f;
    if (t < 128) hv_ = h0in[b * HID + t];
    else if (t < 256) hv_ = h0in[(BATCH + b) * HID + (t - 128)];
    float am = maxwave(__builtin_fabsf(hv_));
    if (ln == 63) maxb[wv] = am;
    if (t < 4) ypartbuf[t] = (t == 0) ? (y0[b] - fcb_) : 0.0f;
    __syncthreads();
    const float bm0 = fmaxf(fmaxf(maxb[0], maxb[1]), 1e-20f);
    const float bm1 = fmaxf(fmaxf(maxb[2], maxb[3]), 1e-20f);
    if (t < 128)
        hsm8[t] = (char)(int)__builtin_rintf(hv_ * (127.0f / bm0));
    else if (t < 256)
        hsm8[256 + (t - 128)] = (char)(int)__builtin_rintf(hv_ * (127.0f / bm1));
    __syncthreads();

    // live scales for the first accumulated product (initial h scale)
    if (isX) {
        SAq1 = SAb1 * (bm0 * INV127);
        SAq2 = SAb2 * (bm0 * INV127);
    } else {
        SBq1 = SBb1 * (bm1 * INV127);
        SBq2 = SBb2 * (bm1 * INV127);
    }

    float* outb = out + (size_t)b * HSTEPS;

    // ---- X preamble: QA = Whh0 @ h0_in(0) ----
    if (isX) {
        i32x4 a0 = *(const i32x4*)&hsm8[16 * grp];
        i32x4 a1 = *(const i32x4*)&hsm8[64 + 16 * grp];
        CH2(QA0, a0, a1, Fq0, Fq1) CH2(QA1, a0, a1, Fq2, Fq3)
        CH2(QA2, a0, a1, Fq4, Fq5) CH2(QA3, a0, a1, Fq6, Fq7)
        CH2(QA4, a0, a1, Fq8, Fq9) CH2(QA5, a0, a1, Fq10, Fq11)
        CH2(QA6, a0, a1, Fq12, Fq13) CH2(QA7, a0, a1, Fq14, Fq15)
    }

    int p = 0;
    int ys = 0;
    int flush_at = YRING;

#pragma unroll 1
    for (int s = 0; s < HSTEPS; ++s) {
        // ================= half 1 =================
        if (isX) {
            // y(s-1); act0(s) [QA from half2(s-1)]; publish h0_out(s)
            float yv = sum4(ypartbuf[ln & 3]) + fcb_;
            if (s > 0) {
                if (t == 0) ybuf[ys] = yv;
                ys = (ys == YRING - 1) ? 0 : ys + 1;
            }
            int a1 = isBt ? (jj ? QA5[0] : QA4[0]) : (jj ? QA1[0] : QA0[0]);
            int a2 = isBt ? (jj ? QA7[0] : QA6[0]) : (jj ? QA3[0] : QA2[0]);
            float G1 = __builtin_fmaf(SAq1, (float)a1,
                                      __builtin_fmaf(E1c, yv, B1c));
            float G2 = __builtin_fmaf(SAq2, (float)a2,
                                      __builtin_fmaf(E2c, yv, B2c));
            float v1 = sigm(G1);  // alpha: si | beta: sigm(2*Gg)
            float v2 = sigm(G2);  // alpha: sf | beta: so
            float tg = __builtin_fmaf(2.f, swzx16(v1), -1.f);  // tanh(Gg)
            Cst = __builtin_fmaf(v2, Cst, v1 * tg);
            float v3 = sigm(2.f * Cst);
            float th = __builtin_fmaf(2.f, v3, -1.f);  // tanh(c)
            float h0n = swzx16(v2) * th;               // so * tanh(c)
            if (!(ln & 16))
                hsm8[(p ^ 1) * 128 + e] =
                    (char)(int)__builtin_rintf(h0n * 127.0f);
            if (s == 0) {
                SAq1 = SAb1 * INV127;
                SAq2 = SAb2 * INV127;
            }
        } else {
            // QB = Whh1 @ h1_in(s)
            const char* h1p = hsm8 + 256 + 128 * p + 16 * grp;
            i32x4 b0_ = *(const i32x4*)(h1p);
            i32x4 b1_ = *(const i32x4*)(h1p + 64);
            CH2(QB0, b0_, b1_, Fq16, Fq17) CH2(QB1, b0_, b1_, Fq18, Fq19)
            CH2(QB2, b0_, b1_, Fq20, Fq21) CH2(QB3, b0_, b1_, Fq22, Fq23)
            CH2(QB4, b0_, b1_, Fq24, Fq25) CH2(QB5, b0_, b1_, Fq26, Fq27)
            CH2(QB6, b0_, b1_, Fq28, Fq29) CH2(QB7, b0_, b1_, Fq30, Fq31)
        }
        __syncthreads();  // B1: h0_out(s) ready

        // ================= half 2 =================
        if (isX) {
            if (s == flush_at) {
                if (t < YRING) outb[flush_at - YRING + t] = ybuf[t];
                flush_at += YRING;
            }
            // QA = Whh0 @ h0_out(s) (pre-work for step s+1)
            const char* h0np = hsm8 + (p ^ 1) * 128 + 16 * grp;
            i32x4 d0 = *(const i32x4*)(h0np);
            i32x4 d1 = *(const i32x4*)(h0np + 64);
            CH2(QA0, d0, d1, Fq0, Fq1) CH2(QA1, d0, d1, Fq2, Fq3)
            CH2(QA2, d0, d1, Fq4, Fq5) CH2(QA3, d0, d1, Fq6, Fq7)
            CH2(QA4, d0, d1, Fq8, Fq9) CH2(QA5, d0, d1, Fq10, Fq11)
            CH2(QA6, d0, d1, Fq12, Fq13) CH2(QA7, d0, d1, Fq14, Fq15)
        } else {
            __builtin_amdgcn_s_setprio(1);
            // QA = Wih1 @ h0_out(s); act1; publish h1_out(s), y-partial
            const char* h0np = hsm8 + (p ^ 1) * 128 + 16 * grp;
            i32x4 d0 = *(const i32x4*)(h0np);
            i32x4 d1 = *(const i32x4*)(h0np + 64);
            CH2(QA0, d0, d1, Fq0, Fq1) CH2(QA1, d0, d1, Fq2, Fq3)
            CH2(QA2, d0, d1, Fq4, Fq5) CH2(QA3, d0, d1, Fq6, Fq7)
            CH2(QA4, d0, d1, Fq8, Fq9) CH2(QA5, d0, d1, Fq10, Fq11)
            CH2(QA6, d0, d1, Fq12, Fq13) CH2(QA7, d0, d1, Fq14, Fq15)
            int a1 = isBt ? (jj ? QA5[0] : QA4[0]) : (jj ? QA1[0] : QA0[0]);
            int a2 = isBt ? (jj ? QA7[0] : QA6[0]) : (jj ? QA3[0] : QA2[0]);
            int c1 = isBt ? (jj ? QB5[0] : QB4[0]) : (jj ? QB1[0] : QB0[0]);
            int c2 = isBt ? (jj ? QB7[0] : QB6[0]) : (jj ? QB3[0] : QB2[0]);
            float H1 = __builtin_fmaf(
                SAq1, (float)a1,
                __builtin_fmaf(SBq1, (float)c1, B1c));
            float H2 = __builtin_fmaf(
                SAq2, (float)a2,
                __builtin_fmaf(SBq2, (float)c2, B2c));
            float v1 = sigm(H1);
            float v2 = sigm(H2);
            float tg = __builtin_fmaf(2.f, swzx16(v1), -1.f);
            Cst = __builtin_fmaf(v2, Cst, v1 * tg);
            float v3 = sigm(2.f * Cst);
            float th = __builtin_fmaf(2.f, v3, -1.f);
            float h1n = swzx16(v2) * th;
            __builtin_amdgcn_s_setprio(0);
            if (!(ln & 16))
                hsm8[256 + (p ^ 1) * 128 + e] =
                    (char)(int)__builtin_rintf(h1n * 127.0f);
            float part = red_wave(E1c * h1n);  // E1c = fcw[e] on alpha, 0 beta
            if (ln == 63) ypartbuf[gw] = part;
            if (s == 0) {
                SBq1 = SBb1 * INV127;
                SBq2 = SBb2 * INV127;
            }
        }
        __syncthreads();  // B2: h1_out(s) + ypart ready
        p ^= 1;
    }

    // ---- tail: y(8639) + final flush ----
    if (isX) {
        float yv = sum4(ypartbuf[ln & 3]) + fcb_;
        if (t == 0) ybuf[YRING - 1] = yv;
    }
    __syncthreads();
    if (t < YRING) outb[HSTEPS - YRING + t] = ybuf[t];
}

extern "C" void kernel_launch(void* const* d_in, const int* in_sizes, int n_in,
                              void* d_out, int out_size, void* d_ws,
                              size_t ws_size, hipStream_t stream) {
    const float* y0 = (const float*)d_in[0];
    const float* h0 = (const float*)d_in[1];
    const float* c0 = (const float*)d_in[2];
    const float* Wih0 = (const float*)d_in[3];
    const float* Whh0 = (const float*)d_in[4];
    const float* bih0 = (const float*)d_in[5];
    const float* bhh0 = (const float*)d_in[6];
    const float* Wih1 = (const float*)d_in[7];
    const float* Whh1 = (const float*)d_in[8];
    const float* bih1 = (const float*)d_in[9];
    const float* bhh1 = (const float*)d_in[10];
    const float* fcw = (const float*)d_in[11];
    const float* fcb = (const float*)d_in[12];
    float* out = (float*)d_out;

    lstm2_kernel<<<dim3(BATCH), dim3(NTHR), 0, stream>>>(
        y0, h0, c0, Wih0, Whh0, bih0, bhh0, Wih1, Whh1, bih1, bhh1, fcw, fcb,
        out);
}